// Round 4
// baseline (264.471 us; speedup 1.0000x reference)
//
#include <hip/hip_runtime.h>
#include <math.h>

// Problem constants (match reference setup_inputs)
constexpr int B = 128, T = 128, F = 2048, KW = 5;
#define ALPHA 0.9f
#define BETA  0.1f
#define DECAY 0.9f
#define GAMMA 0.5f

// One thread per (b,f) series (scalar, 4B/lane, fully coalesced).
// 262144 threads = 4096 waves = 4 waves/SIMD (vs 2 for the float2 version):
// the R2 profile showed Occupancy 20.9% / VALUBusy 21.7% / HBM 36% with
// compulsory-minimal traffic -> latency-bound on grid size. Doubling the
// thread count is the occupancy fix.
// Two passes over t:
//   pass 1: sum_t x  ->  analytic conv-sum (zero-pad edge corrections) -> scale
//   pass 2: rolling 5-tap conv window + LIF recurrence (NO conv[T] array)
// Output stores non-temporal: keeps x resident in L3 so pass 2 re-reads are
// cache-served (verified: FETCH_SIZE == one x read exactly).
__global__ __launch_bounds__(256) void lif_fused_kernel(
    const float* __restrict__ x,        // [B,T,F]
    const float* __restrict__ thr0p,    // scalar
    const float* __restrict__ convw,    // [1,1,KW]
    const float* __restrict__ convb,    // [1]
    const float* __restrict__ sattn,    // [1]
    float* __restrict__ out)            // [B*T*F] spikes ++ [B*F] mem
{
    const int tid = blockIdx.x * blockDim.x + threadIdx.x;
    const int f   = tid & (F - 1);
    const int b   = tid >> 11;           // tid / F, F = 2048

    const float w0 = convw[0], w1 = convw[1], w2 = convw[2],
                w3 = convw[3], w4 = convw[4];
    const float cb   = convb[0];
    const float thr0 = thr0p[0];
    const float sa   = sattn[0];

    const float* xp = x + (size_t)b * T * F + f;

    // ---- pass 1: sum of x over t (4 partial sums for ILP) ----
    float s0 = 0.f, s1 = 0.f, s2 = 0.f, s3 = 0.f;
#pragma unroll 4
    for (int t = 0; t < T; t += 4) {
        s0 += xp[(size_t)(t + 0) * F];
        s1 += xp[(size_t)(t + 1) * F];
        s2 += xp[(size_t)(t + 2) * F];
        s3 += xp[(size_t)(t + 3) * F];
    }
    const float sx = (s0 + s1) + (s2 + s3);

    // edge values (L3-warm re-reads)
    const float e0  = xp[0];
    const float e1  = xp[(size_t)F];
    const float em2 = xp[(size_t)(T - 2) * F];
    const float em1 = xp[(size_t)(T - 1) * F];

    // sum_t conv[t] = W*sum_t x - (w3+w4)x[0] - w4 x[1] - w0 x[T-2] - (w0+w1)x[T-1] + T*cb
    const float W = ((w0 + w1) + (w2 + w3)) + w4;
    const float csum = fmaf(W, sx, (float)T * cb)
                     - (w3 + w4) * e0 - w4 * e1 - w0 * em2 - (w0 + w1) * em1;

    // ---- spatial attention gate ----
    const float z     = sa * (csum * (1.0f / (float)T));
    const float watt  = 1.0f / (1.0f + expf(-z));
    const float scale = 1.0f + GAMMA * watt;

    // ---- pass 2: rolling conv + LIF recurrence ----
    const float PI  = 3.14159265358979323846f;
    const float thc = (1.0f - ALPHA) * thr0;

    float mem = 0.f, thr = thr0;
    float h0 = 0.f, h1 = 0.f, h2 = 0.f;
    // window regs: a=x[t-2], bb=x[t-1], c=x[t], d=x[t+1]
    float a = 0.f, bb = 0.f, c = e0, d = e1;

    float* sp = out + (size_t)b * T * F + f;                  // spikes [B,T,F]
    float* mp = out + (size_t)B * T * F + (size_t)b * F + f;  // mem [B,F]

    auto lif_step = [&](int t, float e) {
        float ct = fmaf(w0, a, fmaf(w1, bb, fmaf(w2, c,
                   fmaf(w3, d, fmaf(w4, e, cb)))));
        mem = fmaf(DECAY, mem, ct * scale);
        float sarg  = PI * (mem - thr) * 0.5f;
        float spike = 0.5f * (atanf(sarg) * (1.0f / PI) + 0.5f);
        h0 = h1; h1 = h2; h2 = spike;
        float avg = (h0 + h1 + h2) * (1.0f / 3.0f);
        thr = fmaf(ALPHA, thr, fmaf(BETA, avg, thc));
        mem = fmaf(-spike, thr, mem);
        // non-temporal: spikes are write-once streaming; don't evict x from L3
        __builtin_nontemporal_store(spike, sp + (size_t)t * F);
        a = bb; bb = c; c = d; d = e;
    };

#pragma unroll 8
    for (int t = 0; t < T - 2; ++t) {
        float e = xp[(size_t)(t + 2) * F];
        lif_step(t, e);
    }
    lif_step(T - 2, 0.f);   // e = 0 (zero pad)
    lif_step(T - 1, 0.f);   // d = e = 0

    __builtin_nontemporal_store(mem, mp);
}

extern "C" void kernel_launch(void* const* d_in, const int* in_sizes, int n_in,
                              void* d_out, int out_size, void* d_ws, size_t ws_size,
                              hipStream_t stream) {
    const float* x     = (const float*)d_in[0];
    const float* thr0  = (const float*)d_in[1];
    const float* convw = (const float*)d_in[2];
    const float* convb = (const float*)d_in[3];
    const float* sattn = (const float*)d_in[4];
    float* out = (float*)d_out;

    const int total = B * F;            // one thread per (b,f)
    const int block = 256;
    const int grid  = total / block;    // 1024 blocks

    lif_fused_kernel<<<grid, block, 0, stream>>>(x, thr0, convw, convb, sattn, out);
}

// Round 6
// 251.850 us; speedup vs baseline: 1.0501x; 1.0501x over previous
//
#include <hip/hip_runtime.h>
#include <math.h>

// Problem constants (match reference setup_inputs)
constexpr int B = 128, T = 128, F = 2048, KW = 5;
#define ALPHA 0.9f
#define BETA  0.1f
#define DECAY 0.9f
#define GAMMA 0.5f

// native clang vector type (nontemporal builtin rejects HIP float2)
typedef float v2f __attribute__((ext_vector_type(2)));

// One thread per 2 consecutive (b,f) series (8B/lane). 131072 threads =
// 2048 waves = 2 waves/SIMD (grid-limited; measured best at 93us vs 103us
// for the 1-series 4-wave variant). This version deepens the per-thread
// memory pipeline instead of adding waves:
//  - __launch_bounds__(256,2): VGPR budget 128, not the 24-32 the compiler
//    picks when unconstrained (that starved loads-in-flight).
//  - pass 2 uses an 8-deep double-buffered register prefetch ring: the 8
//    L3-hit loads of group g+1 are issued before the compute of group g,
//    amortizing ~450cy L3 latency over 8 LIF steps.
// HBM traffic verified compulsory-minimal (FETCH==x, WRITE==out); stores
// non-temporal so the spike stream doesn't evict x from L3.
__global__ __launch_bounds__(256, 2) void lif_fused_kernel(
    const float* __restrict__ x,        // [B,T,F]
    const float* __restrict__ thr0p,    // scalar
    const float* __restrict__ convw,    // [1,1,KW]
    const float* __restrict__ convb,    // [1]
    const float* __restrict__ sattn,    // [1]
    float* __restrict__ out)            // [B*T*F] spikes ++ [B*F] mem
{
    const int tid   = blockIdx.x * blockDim.x + threadIdx.x;
    const int fpair = tid & (F / 2 - 1);    // 0..1023
    const int b     = tid >> 10;            // tid / (F/2)
    const int f     = fpair * 2;

    const float w0 = convw[0], w1 = convw[1], w2 = convw[2],
                w3 = convw[3], w4 = convw[4];
    const float cb   = convb[0];
    const float thr0 = thr0p[0];
    const float sa   = sattn[0];

    const float* xp = x + (size_t)b * T * F + f;

    // ---- pass 1: sum of x over t (8 partial sums, 8 loads in flight) ----
    v2f s0 = {0.f,0.f}, s1 = {0.f,0.f}, s2 = {0.f,0.f}, s3 = {0.f,0.f},
        s4 = {0.f,0.f}, s5 = {0.f,0.f}, s6 = {0.f,0.f}, s7 = {0.f,0.f};
#pragma unroll 2
    for (int t = 0; t < T; t += 8) {
        v2f v0 = *(const v2f*)(xp + (size_t)(t + 0) * F);
        v2f v1 = *(const v2f*)(xp + (size_t)(t + 1) * F);
        v2f v2 = *(const v2f*)(xp + (size_t)(t + 2) * F);
        v2f v3 = *(const v2f*)(xp + (size_t)(t + 3) * F);
        v2f v4 = *(const v2f*)(xp + (size_t)(t + 4) * F);
        v2f v5 = *(const v2f*)(xp + (size_t)(t + 5) * F);
        v2f v6 = *(const v2f*)(xp + (size_t)(t + 6) * F);
        v2f v7 = *(const v2f*)(xp + (size_t)(t + 7) * F);
        s0 += v0; s1 += v1; s2 += v2; s3 += v3;
        s4 += v4; s5 += v5; s6 += v6; s7 += v7;
    }
    v2f sx = ((s0 + s1) + (s2 + s3)) + ((s4 + s5) + (s6 + s7));

    // edge values (L3-warm re-reads)
    v2f e0  = *(const v2f*)(xp);                      // x[0]
    v2f e1  = *(const v2f*)(xp + (size_t)F);          // x[1]
    v2f em2 = *(const v2f*)(xp + (size_t)(T - 2) * F);// x[T-2]
    v2f em1 = *(const v2f*)(xp + (size_t)(T - 1) * F);// x[T-1]

    // sum_t conv[t] = W*sum_t x - (w3+w4)x[0] - w4 x[1] - w0 x[T-2] - (w0+w1)x[T-1] + T*cb
    const float W = ((w0 + w1) + (w2 + w3)) + w4;
    v2f csum;
    csum.x = fmaf(W, sx.x, (float)T * cb)
           - (w3 + w4) * e0.x - w4 * e1.x - w0 * em2.x - (w0 + w1) * em1.x;
    csum.y = fmaf(W, sx.y, (float)T * cb)
           - (w3 + w4) * e0.y - w4 * e1.y - w0 * em2.y - (w0 + w1) * em1.y;

    // ---- spatial attention gate ----
    v2f scale;
    {
        float zx = sa * (csum.x * (1.0f / (float)T));
        float zy = sa * (csum.y * (1.0f / (float)T));
        scale.x = 1.0f + GAMMA * (1.0f / (1.0f + expf(-zx)));
        scale.y = 1.0f + GAMMA * (1.0f / (1.0f + expf(-zy)));
    }

    // ---- pass 2: rolling conv + LIF with 8-deep prefetch ring ----
    const float PI  = 3.14159265358979323846f;
    const float thc = (1.0f - ALPHA) * thr0;

    v2f mem = {0.f, 0.f};
    v2f thr = {thr0, thr0};
    v2f h1 = {0.f, 0.f}, h2 = {0.f, 0.f};
    // window regs: a=x[t-2], bb=x[t-1], c=x[t], d=x[t+1]
    v2f a = {0.f, 0.f}, bb = {0.f, 0.f}, c = e0, d = e1;

    float* sp = out + (size_t)b * T * F + f;                  // spikes [B,T,F]
    float* mp = out + (size_t)B * T * F + (size_t)b * F + f;  // mem [B,F]

    auto lif_step = [&](int t, v2f e) {
        float cx = fmaf(w0, a.x, fmaf(w1, bb.x, fmaf(w2, c.x,
                   fmaf(w3, d.x, fmaf(w4, e.x, cb)))));
        float cy = fmaf(w0, a.y, fmaf(w1, bb.y, fmaf(w2, c.y,
                   fmaf(w3, d.y, fmaf(w4, e.y, cb)))));
        mem.x = fmaf(DECAY, mem.x, cx * scale.x);
        mem.y = fmaf(DECAY, mem.y, cy * scale.y);
        float sgx = PI * (mem.x - thr.x) * 0.5f;
        float sgy = PI * (mem.y - thr.y) * 0.5f;
        float spx = 0.5f * (atanf(sgx) * (1.0f / PI) + 0.5f);
        float spy = 0.5f * (atanf(sgy) * (1.0f / PI) + 0.5f);
        float avx = (h1.x + h2.x + spx) * (1.0f / 3.0f);
        float avy = (h1.y + h2.y + spy) * (1.0f / 3.0f);
        h1 = h2; h2.x = spx; h2.y = spy;
        thr.x = fmaf(ALPHA, thr.x, fmaf(BETA, avx, thc));
        thr.y = fmaf(ALPHA, thr.y, fmaf(BETA, avy, thc));
        mem.x = fmaf(-spx, thr.x, mem.x);
        mem.y = fmaf(-spy, thr.y, mem.y);
        v2f spv = {spx, spy};
        __builtin_nontemporal_store(spv, (v2f*)(sp + (size_t)t * F));
        a = bb; bb = c; c = d; d = e;
    };

    // group g covers t = 8g..8g+7 and consumes e = x[8g+2 .. 8g+9]
    v2f A[8], Bv[8];

#define LOADG(buf, base)                                        \
    _Pragma("unroll")                                           \
    for (int j = 0; j < 8; ++j)                                 \
        buf[j] = *(const v2f*)(xp + (size_t)((base) + j) * F);

#define COMPUTE8(buf, t0)                                       \
    _Pragma("unroll")                                           \
    for (int j = 0; j < 8; ++j)                                 \
        lif_step((t0) + j, buf[j]);

    LOADG(A, 2);                       // group 0: e = x[2..9]
    for (int p = 0; p < 7; ++p) {      // pairs of groups (2p, 2p+1)
        const int t0 = 16 * p;
        LOADG(Bv, t0 + 10);            // group 2p+1: e = x[t0+10 .. t0+17]
        COMPUTE8(A, t0);               // group 2p
        LOADG(A, t0 + 18);             // group 2p+2: e = x[t0+18 .. t0+25]
        COMPUTE8(Bv, t0 + 8);          // group 2p+1
    }
    // peel last pair: groups 14 (A holds e=x[114..121]) and 15
#pragma unroll
    for (int j = 0; j < 8; ++j) {      // group 15: e = x[122..129], pad 0
        if (j < 6) Bv[j] = *(const v2f*)(xp + (size_t)(122 + j) * F);
        else       Bv[j] = (v2f){0.f, 0.f};
    }
    COMPUTE8(A, 112);
    COMPUTE8(Bv, 120);

#undef LOADG
#undef COMPUTE8

    __builtin_nontemporal_store(mem, (v2f*)mp);
}

extern "C" void kernel_launch(void* const* d_in, const int* in_sizes, int n_in,
                              void* d_out, int out_size, void* d_ws, size_t ws_size,
                              hipStream_t stream) {
    const float* x     = (const float*)d_in[0];
    const float* thr0  = (const float*)d_in[1];
    const float* convw = (const float*)d_in[2];
    const float* convb = (const float*)d_in[3];
    const float* sattn = (const float*)d_in[4];
    float* out = (float*)d_out;

    const int total = B * F / 2;        // one thread per 2 (b,f) series
    const int block = 256;
    const int grid  = total / block;    // 512 blocks

    lif_fused_kernel<<<grid, block, 0, stream>>>(x, thr0, convw, convb, sattn, out);
}